// Round 6
// baseline (64.081 us; speedup 1.0000x reference)
//
#include <hip/hip_runtime.h>
#include <math.h>

#define TT 1024
#define DD 128

static constexpr float kNegInf = -1e9f;

__device__ __forceinline__ unsigned short f2bf(float x) {
  unsigned int u = __float_as_uint(x);
  u = (u + 0x7FFF + ((u >> 16) & 1)) >> 16;   // RNE
  return (unsigned short)u;
}

// ---- K0: transpose + bf16 cast + wj/swj/bias, 32 rows per block ----
__global__ __launch_bounds__(256) void k_prep(const float* __restrict__ h,
                                              const float* __restrict__ w,
                                              const int* __restrict__ mk,
                                              float4* __restrict__ hT4,
                                              ushort4* __restrict__ hbf,
                                              float* __restrict__ swj,
                                              float* __restrict__ bias) {
  __shared__ __align__(16) float tile[32 * 132];
  __shared__ float wred[32 * 8];
  const int b  = blockIdx.x >> 5;
  const int jt = blockIdx.x & 31;
  const size_t base = (size_t)(b * TT + jt * 32) * 32;  // float4 units
  const float4* src = (const float4*)h + base;
#pragma unroll
  for (int k = 0; k < 4; ++k) {
    int idx = k * 256 + threadIdx.x;     // 0..1023
    float4 v = src[idx];
    int j = idx >> 5, c = idx & 31;
    *((float4*)&tile[j * 132 + c * 4]) = v;
    ushort4 bv;
    bv.x = f2bf(v.x); bv.y = f2bf(v.y); bv.z = f2bf(v.z); bv.w = f2bf(v.w);
    hbf[base + idx] = bv;
  }
  __syncthreads();
  const int j  = threadIdx.x & 31;       // row in tile
  const int dg = threadIdx.x >> 5;       // 0..7
#pragma unroll
  for (int k = 0; k < 4; ++k) {
    int dq = dg * 4 + k;                 // 0..31
    hT4[(size_t)(b * 32 + dq) * TT + jt * 32 + j] =
        *((const float4*)&tile[j * 132 + dq * 4]);
  }
  // wj partial: thread = (row j, dim-eighth dg)
  float p = 0.f;
#pragma unroll
  for (int e = 0; e < 16; e += 4) {
    float4 hv = *(const float4*)&tile[j * 132 + dg * 16 + e];
    float4 wv = *(const float4*)&w[dg * 16 + e];
    p += hv.x * wv.x + hv.y * wv.y + hv.z * wv.z + hv.w * wv.w;
  }
  wred[j * 8 + dg] = p;
  __syncthreads();
  if (threadIdx.x < 32) {
    const int row = b * TT + jt * 32 + threadIdx.x;
    float a = 0.f;
#pragma unroll
    for (int e = 0; e < 8; ++e) a += wred[threadIdx.x * 8 + e];
    const bool ok = (mk[row] != 0);
    swj[row]  = ok ? -a : 0.f;
    bias[row] = ok ? 0.f : kNegInf;
  }
}

// ---- K1: partial fused attention: 16 rows x 256 j's per block ----
// grid = (128 rowgroups) x (4 j-splits) = 512 blocks, 512 threads.
__global__ __launch_bounds__(512) void k_fused(const float* __restrict__ h,
                                               const float4* __restrict__ hT4,
                                               const unsigned short* __restrict__ hbf,
                                               const float* __restrict__ swj,
                                               const float* __restrict__ bias,
                                               float* __restrict__ ctxpart,
                                               float* __restrict__ mlpart) {
  __shared__ __align__(16) float Pt[256 * 16];       // 16 KB, [jq][slot swz]
  __shared__ __align__(16) float ctxp[4 * 16 * DD];  // 32 KB, [g][row][d]
  __shared__ float wredm[8][8];
  __shared__ float wreds[8][8];

  const int tid = threadIdx.x;
  const int rg  = blockIdx.x & 127;          // row-group (16 rows)
  const int js  = blockIdx.x >> 7;           // j-split 0..3
  const int b   = rg >> 6;
  const int lrow0 = (rg & 63) * 16;          // first row within batch
  const float* hb = h + (size_t)b * TT * DD;
  const float* hA = hb + (size_t)lrow0 * DD; // block-uniform A base

  const int jq   = tid & 255;                // j within block
  const int rh   = tid >> 8;                 // row half 0/1
  const int jloc = js * 256 + jq;            // j within batch
  const float4* hjb = hT4 + (size_t)b * 32 * TT;

  // ---------------- phase 1: distances for 8 rows x 1 j ----------------
  float acc[8];
#pragma unroll
  for (int r = 0; r < 8; ++r) acc[r] = 0.f;
  {
    float4 B0a = hjb[(size_t)0 * TT + jloc];
    float4 B0b = hjb[(size_t)1 * TT + jloc];
    float4 B1a, B1b;
#pragma unroll 1
    for (int c = 0; c < 16; ++c) {
      if (c < 15) {
        B1a = hjb[(size_t)(c * 2 + 2) * TT + jloc];
        B1b = hjb[(size_t)(c * 2 + 3) * TT + jloc];
      }
#pragma unroll
      for (int r = 0; r < 8; ++r) {
        const float* Ar = &hA[(size_t)(rh * 8 + r) * DD + c * 8];
        const float4 A0 = *(const float4*)&Ar[0];
        const float4 A1 = *(const float4*)&Ar[4];
        float s = acc[r];
        s += fabsf(A0.x - B0a.x) + fabsf(A0.y - B0a.y) +
             fabsf(A0.z - B0a.z) + fabsf(A0.w - B0a.w);
        s += fabsf(A1.x - B0b.x) + fabsf(A1.y - B0b.y) +
             fabsf(A1.z - B0b.z) + fabsf(A1.w - B0b.w);
        acc[r] = s;
      }
      B0a = B1a; B0b = B1b;
    }
  }

  // scores
  const float sw = swj[b * TT + jloc];
  const float bv = bias[b * TT + jloc];
  float sc[8];
#pragma unroll
  for (int r = 0; r < 8; ++r) sc[r] = fmaf(sw, acc[r], bv);

  // per-wave max reduce -> LDS
  const int wv = tid >> 6;
  {
    float mm[8];
#pragma unroll
    for (int r = 0; r < 8; ++r) {
      float m0 = sc[r];
#pragma unroll
      for (int off = 32; off; off >>= 1) m0 = fmaxf(m0, __shfl_xor(m0, off));
      mm[r] = m0;
    }
    if ((tid & 63) == 0) {
#pragma unroll
      for (int r = 0; r < 8; ++r) wredm[wv][r] = mm[r];
    }
  }
  __syncthreads();

  float m[8];
  const int w0 = rh * 4;
#pragma unroll
  for (int r = 0; r < 8; ++r)
    m[r] = fmaxf(fmaxf(wredm[w0][r], wredm[w0 + 1][r]),
                 fmaxf(wredm[w0 + 2][r], wredm[w0 + 3][r]));

  // exp + write swizzled Pt + partial sums
  const int gsw = (jq >> 1) & 3;             // store-swizzle for bank spread
  float psum[8];
#pragma unroll
  for (int r = 0; r < 8; ++r) {
    const float p = __expf(sc[r] - m[r]);
    const int slot = ((((rh * 8 + r) >> 2) ^ gsw) << 2) | ((rh * 8 + r) & 3);
    Pt[jq * 16 + slot] = p;
    psum[r] = p;
  }
#pragma unroll
  for (int r = 0; r < 8; ++r) {
#pragma unroll
    for (int off = 32; off; off >>= 1) psum[r] += __shfl_xor(psum[r], off);
  }
  if ((tid & 63) == 0) {
#pragma unroll
    for (int r = 0; r < 8; ++r) wreds[wv][r] = psum[r];
  }
  __syncthreads();

  // write m/l partials for the merge kernel
  const int slotid = js * 128 + rg;
  if (tid < 8) {
    const int r = tid;
    mlpart[slotid * 32 + r] =
        fmaxf(fmaxf(wredm[0][r], wredm[1][r]), fmaxf(wredm[2][r], wredm[3][r]));
    mlpart[slotid * 32 + 16 + r] =
        wreds[0][r] + wreds[1][r] + wreds[2][r] + wreds[3][r];
  } else if (tid >= 256 && tid < 264) {
    const int r = tid - 256;
    mlpart[slotid * 32 + 8 + r] =
        fmaxf(fmaxf(wredm[4][r], wredm[5][r]), fmaxf(wredm[6][r], wredm[7][r]));
    mlpart[slotid * 32 + 24 + r] =
        wreds[4][r] + wreds[5][r] + wreds[6][r] + wreds[7][r];
  }

  // ---------------- PV: thread = (dpair x rowhalf x g), 64 j each --------
  const int dpair = tid & 63;                // dim pair (2 dims)
  const int rh2   = (tid >> 6) & 1;          // row half
  const int g     = tid >> 7;                // j slice 0..3
  float cacc[8][2];
#pragma unroll
  for (int r = 0; r < 8; ++r) { cacc[r][0] = 0.f; cacc[r][1] = 0.f; }
  const unsigned short* hb16 = hbf + (size_t)b * TT * DD;

  {
    auto ldP = [&](float4& Pa, float4& Pb, unsigned int& V, int jj) {
      const int jql = g * 64 + jj;
      const int swz = (jql >> 1) & 3;
      const int grpA = ((rh2 * 2 + 0) ^ swz) << 2;
      const int grpB = ((rh2 * 2 + 1) ^ swz) << 2;
      Pa = *(const float4*)&Pt[jql * 16 + grpA];
      Pb = *(const float4*)&Pt[jql * 16 + grpB];
      V  = *(const unsigned int*)&hb16[(size_t)(js * 256 + jql) * DD + dpair * 2];
    };
    auto pvc = [&](const float4& Pa, const float4& Pb, unsigned int V) {
      const float h0 = __uint_as_float(V << 16);
      const float h1 = __uint_as_float(V & 0xFFFF0000u);
      cacc[0][0] = fmaf(Pa.x, h0, cacc[0][0]);
      cacc[0][1] = fmaf(Pa.x, h1, cacc[0][1]);
      cacc[1][0] = fmaf(Pa.y, h0, cacc[1][0]);
      cacc[1][1] = fmaf(Pa.y, h1, cacc[1][1]);
      cacc[2][0] = fmaf(Pa.z, h0, cacc[2][0]);
      cacc[2][1] = fmaf(Pa.z, h1, cacc[2][1]);
      cacc[3][0] = fmaf(Pa.w, h0, cacc[3][0]);
      cacc[3][1] = fmaf(Pa.w, h1, cacc[3][1]);
      cacc[4][0] = fmaf(Pb.x, h0, cacc[4][0]);
      cacc[4][1] = fmaf(Pb.x, h1, cacc[4][1]);
      cacc[5][0] = fmaf(Pb.y, h0, cacc[5][0]);
      cacc[5][1] = fmaf(Pb.y, h1, cacc[5][1]);
      cacc[6][0] = fmaf(Pb.z, h0, cacc[6][0]);
      cacc[6][1] = fmaf(Pb.z, h1, cacc[6][1]);
      cacc[7][0] = fmaf(Pb.w, h0, cacc[7][0]);
      cacc[7][1] = fmaf(Pb.w, h1, cacc[7][1]);
    };
    float4 Pa0, Pb0, Pa1, Pb1; unsigned int V0, V1;
    ldP(Pa0, Pb0, V0, 0);
#pragma unroll 1
    for (int jj = 0; jj < 64; jj += 2) {
      ldP(Pa1, Pb1, V1, jj + 1);           // jj+1 <= 63: always valid
      pvc(Pa0, Pb0, V0);
      if (jj < 62) ldP(Pa0, Pb0, V0, jj + 2);
      pvc(Pa1, Pb1, V1);
    }
  }

#pragma unroll
  for (int r = 0; r < 8; ++r) {
    float2 cv = {cacc[r][0], cacc[r][1]};
    *(float2*)&ctxp[(size_t)(g * 16 + rh2 * 8 + r) * DD + dpair * 2] = cv;
  }
  __syncthreads();

  // final: reduce 4 j-slices, write ctx partial
#pragma unroll
  for (int k = 0; k < 4; ++k) {
    const int idx = tid + k * 512;           // 0..2047
    const int r  = idx >> 7;
    const int dd = idx & 127;
    const float s = ctxp[(size_t)(0 * 16 + r) * DD + dd] +
                    ctxp[(size_t)(1 * 16 + r) * DD + dd] +
                    ctxp[(size_t)(2 * 16 + r) * DD + dd] +
                    ctxp[(size_t)(3 * 16 + r) * DD + dd];
    ctxpart[((size_t)slotid * 16 + r) * DD + dd] = s;
  }
}

// ---- K2: merge 4 j-split partials, normalize, write concat(h, ctx) ----
__global__ __launch_bounds__(256) void k_merge(const float* __restrict__ h,
                                               const float* __restrict__ ctxpart,
                                               const float* __restrict__ mlpart,
                                               float* __restrict__ out) {
  const int row = blockIdx.x * 2 + (threadIdx.x >> 7);   // 0..2047
  const int dd  = threadIdx.x & 127;
  const int rg  = row >> 4;
  const int r   = row & 15;

  float mg[4], lg[4];
#pragma unroll
  for (int g = 0; g < 4; ++g) {
    const int sid = g * 128 + rg;
    mg[g] = mlpart[sid * 32 + r];
    lg[g] = mlpart[sid * 32 + 16 + r];
  }
  const float M = fmaxf(fmaxf(mg[0], mg[1]), fmaxf(mg[2], mg[3]));
  float L = 0.f, c = 0.f;
#pragma unroll
  for (int g = 0; g < 4; ++g) {
    const float wg = __expf(mg[g] - M);
    L = fmaf(lg[g], wg, L);
    c = fmaf(ctxpart[((size_t)(g * 128 + rg) * 16 + r) * DD + dd], wg, c);
  }
  out[(size_t)row * 256 + dd]       = h[(size_t)row * DD + dd];
  out[(size_t)row * 256 + 128 + dd] = c / L;
}

extern "C" void kernel_launch(void* const* d_in, const int* in_sizes, int n_in,
                              void* d_out, int out_size, void* d_ws, size_t ws_size,
                              hipStream_t stream) {
  const float* h  = (const float*)d_in[0];
  const int*   mk = (const int*)d_in[1];
  const float* w  = (const float*)d_in[2];
  float* out = (float*)d_out;

  char* ws = (char*)d_ws;
  float*   swj  = (float*)ws;                              // 8 KB
  float*   bias = (float*)(ws + 8192);                     // 8 KB
  float4*  hT4  = (float4*)(ws + 16384);                   // 1 MB
  ushort4* hbf  = (ushort4*)(ws + 16384 + (size_t)1048576);            // 512 KB
  float* ctxpart = (float*)(ws + 16384 + 1048576 + 524288);            // 4 MB
  float* mlpart  = (float*)(ws + 16384 + 1048576 + 524288 + 4194304);  // 64 KB

  hipLaunchKernelGGL(k_prep,  dim3(64),   dim3(256), 0, stream,
                     h, w, mk, hT4, hbf, swj, bias);
  hipLaunchKernelGGL(k_fused, dim3(512),  dim3(512), 0, stream, h, hT4,
                     (const unsigned short*)hbf, swj, bias, ctxpart, mlpart);
  hipLaunchKernelGGL(k_merge, dim3(1024), dim3(256), 0, stream,
                     h, ctxpart, mlpart, out);
}

// Round 8
// 49.236 us; speedup vs baseline: 1.3015x; 1.3015x over previous
//
#include <hip/hip_runtime.h>
#include <math.h>

#define TT 1024
#define DD 128

static constexpr float kNegInf = -1e9f;

typedef __fp16 h2 __attribute__((ext_vector_type(2)));

__device__ __forceinline__ unsigned int pk16(float a, float b) {
  h2 v = __builtin_amdgcn_cvt_pkrtz(a, b);
  return __builtin_bit_cast(unsigned int, v);
}

__device__ __forceinline__ float dot2f(unsigned int a, unsigned int b, float c) {
#if __has_builtin(__builtin_amdgcn_fdot2)
  return __builtin_amdgcn_fdot2(__builtin_bit_cast(h2, a),
                                __builtin_bit_cast(h2, b), c, false);
#else
  h2 av = __builtin_bit_cast(h2, a), bv = __builtin_bit_cast(h2, b);
  return c + (float)av.x * (float)bv.x + (float)av.y * (float)bv.y;
#endif
}

// ---- K0: transpose (f32 [dq][j]) + f16 j-pair pack ([jp][d]) + swj/bias ----
__global__ __launch_bounds__(256) void k_prep(const float* __restrict__ h,
                                              const float* __restrict__ w,
                                              const int* __restrict__ mk,
                                              float4* __restrict__ hT4,
                                              unsigned int* __restrict__ hT16,
                                              float* __restrict__ swj,
                                              float* __restrict__ bias) {
  __shared__ __align__(16) float tile[32 * 132];
  __shared__ float wred[32 * 8];
  const int b  = blockIdx.x >> 5;
  const int jt = blockIdx.x & 31;
  const size_t base = (size_t)(b * TT + jt * 32) * 32;  // float4 units
  const float4* src = (const float4*)h + base;
#pragma unroll
  for (int k = 0; k < 4; ++k) {
    int idx = k * 256 + threadIdx.x;     // 0..1023
    float4 v = src[idx];
    int j = idx >> 5, c = idx & 31;
    *((float4*)&tile[j * 132 + c * 4]) = v;
  }
  __syncthreads();
  const int j  = threadIdx.x & 31;       // row in tile
  const int dg = threadIdx.x >> 5;       // 0..7
#pragma unroll
  for (int k = 0; k < 4; ++k) {
    int dq = dg * 4 + k;                 // 0..31
    hT4[(size_t)(b * 32 + dq) * TT + jt * 32 + j] =
        *((const float4*)&tile[j * 132 + dq * 4]);
  }
  // hT16[jp][d]: pack rows (2jl, 2jl+1) at dim d into one f16x2 word
#pragma unroll
  for (int k = 0; k < 8; ++k) {
    int idx = k * 256 + threadIdx.x;     // 0..2047
    int jl = idx >> 7, d = idx & 127;
    hT16[((size_t)b * 512 + jt * 16 + jl) * 128 + d] =
        pk16(tile[(2 * jl) * 132 + d], tile[(2 * jl + 1) * 132 + d]);
  }
  // wj partial: thread = (row j, dim-eighth dg)
  float p = 0.f;
#pragma unroll
  for (int e = 0; e < 16; e += 4) {
    float4 hv = *(const float4*)&tile[j * 132 + dg * 16 + e];
    float4 wv = *(const float4*)&w[dg * 16 + e];
    p += hv.x * wv.x + hv.y * wv.y + hv.z * wv.z + hv.w * wv.w;
  }
  wred[j * 8 + dg] = p;
  __syncthreads();
  if (threadIdx.x < 32) {
    const int row = b * TT + jt * 32 + threadIdx.x;
    float a = 0.f;
#pragma unroll
    for (int e = 0; e < 8; ++e) a += wred[threadIdx.x * 8 + e];
    const bool ok = (mk[row] != 0);
    swj[row]  = ok ? -a : 0.f;
    bias[row] = ok ? 0.f : kNegInf;
  }
}

// ---- K1: partial fused attn: 8 rows x 256 j per block, 1024 blocks ----
__global__ __launch_bounds__(256, 4) void k_fused(
    const float* __restrict__ h, const float4* __restrict__ hT4,
    const unsigned int* __restrict__ hT16,
    const float* __restrict__ swj, const float* __restrict__ bias,
    float* __restrict__ ctxpart, float* __restrict__ mlpart) {
  __shared__ __align__(16) unsigned int Pt[128][8];   // 4 KB [jp][row]
  __shared__ __align__(16) float ctxp[4][8][DD];      // 16 KB [g][row][d]
  __shared__ float wredm[4][4];
  __shared__ float wreds[4][4];

  const int tid  = threadIdx.x;
  const int rgid = blockIdx.x & 255;         // global rowgroup (8 rows)
  const int js   = blockIdx.x >> 8;          // j-split 0..3
  const int b    = rgid >> 7;
  const int lrow0 = (rgid & 127) * 8;
  const float* hA = h + ((size_t)b * TT + lrow0) * DD;
  const int jp_t = tid & 127;                // j-pair index in 256-j tile
  const int rh   = tid >> 7;                 // row half: rows rh*4..rh*4+3
  const int j0   = js * 256 + jp_t * 2;      // j within batch
  const float4* hjb = hT4 + (size_t)b * 32 * TT;

  // ---------------- phase 1: distances, J=2 x RB=4 ----------------
  float acc[2][4];
#pragma unroll
  for (int u = 0; u < 2; ++u)
#pragma unroll
    for (int r = 0; r < 4; ++r) acc[u][r] = 0.f;

#define LOADB(B, c) {                                       \
    B[0][0] = hjb[(size_t)((c) * 2    ) * TT + j0    ];     \
    B[1][0] = hjb[(size_t)((c) * 2    ) * TT + j0 + 1];     \
    B[0][1] = hjb[(size_t)((c) * 2 + 1) * TT + j0    ];     \
    B[1][1] = hjb[(size_t)((c) * 2 + 1) * TT + j0 + 1]; }

#define COMPD(B, c) {                                                   \
    _Pragma("unroll") for (int r = 0; r < 4; ++r) {                     \
      const float4 A0 = *(const float4*)&hA[(rh * 4 + r) * DD + (c) * 8];     \
      const float4 A1 = *(const float4*)&hA[(rh * 4 + r) * DD + (c) * 8 + 4]; \
      _Pragma("unroll") for (int u = 0; u < 2; ++u) {                   \
        float s = acc[u][r];                                            \
        s += fabsf(A0.x - B[u][0].x) + fabsf(A0.y - B[u][0].y) +        \
             fabsf(A0.z - B[u][0].z) + fabsf(A0.w - B[u][0].w);         \
        s += fabsf(A1.x - B[u][1].x) + fabsf(A1.y - B[u][1].y) +        \
             fabsf(A1.z - B[u][1].z) + fabsf(A1.w - B[u][1].w);         \
        acc[u][r] = s; } } }

  {
    float4 B0[2][2], B1[2][2];
    LOADB(B0, 0);
#pragma unroll 1
    for (int cc = 0; cc < 8; ++cc) {
      LOADB(B1, 2 * cc + 1);               // unconditional: 2cc+1 <= 15
      COMPD(B0, 2 * cc);
      if (cc < 7) LOADB(B0, 2 * cc + 2);
      COMPD(B1, 2 * cc + 1);
    }
  }

  // scores
  const float sw0 = swj[b * TT + j0],  sw1 = swj[b * TT + j0 + 1];
  const float bv0 = bias[b * TT + j0], bv1 = bias[b * TT + j0 + 1];
  float sc[2][4];
#pragma unroll
  for (int r = 0; r < 4; ++r) {
    sc[0][r] = fmaf(sw0, acc[0][r], bv0);
    sc[1][r] = fmaf(sw1, acc[1][r], bv1);
  }

  // row max: wave reduce, then combine wave pairs via LDS
  const int wv = tid >> 6;
  {
    float mm[4];
#pragma unroll
    for (int r = 0; r < 4; ++r) {
      float m0 = fmaxf(sc[0][r], sc[1][r]);
#pragma unroll
      for (int off = 32; off; off >>= 1) m0 = fmaxf(m0, __shfl_xor(m0, off));
      mm[r] = m0;
    }
    if ((tid & 63) == 0) {
#pragma unroll
      for (int r = 0; r < 4; ++r) wredm[wv][r] = mm[r];
    }
  }
  __syncthreads();
  float m[4];
#pragma unroll
  for (int r = 0; r < 4; ++r)
    m[r] = fmaxf(wredm[rh * 2][r], wredm[rh * 2 + 1][r]);

  // exp + pack f16 j-pairs + one b128 Pt write + partial sums
  {
    float ps[4];
    unsigned int pk[4];
#pragma unroll
    for (int r = 0; r < 4; ++r) {
      const float p0 = __expf(sc[0][r] - m[r]);
      const float p1 = __expf(sc[1][r] - m[r]);
      pk[r] = pk16(p0, p1);
      ps[r] = p0 + p1;
    }
    uint4 pw = {pk[0], pk[1], pk[2], pk[3]};
    *(uint4*)&Pt[jp_t][rh * 4] = pw;
#pragma unroll
    for (int r = 0; r < 4; ++r) {
#pragma unroll
      for (int off = 32; off; off >>= 1) ps[r] += __shfl_xor(ps[r], off);
    }
    if ((tid & 63) == 0) {
#pragma unroll
      for (int r = 0; r < 4; ++r) wreds[wv][r] = ps[r];
    }
  }
  __syncthreads();

  const int slot = js * 256 + rgid;
  if (tid < 8) {
    const int r = tid, w0 = (r >> 2) * 2, rr = r & 3;
    mlpart[slot * 16 + r]     = fmaxf(wredm[w0][rr], wredm[w0 + 1][rr]);
    mlpart[slot * 16 + 8 + r] = wreds[w0][rr] + wreds[w0 + 1][rr];
  }

  // ---------------- PV via dot2: thread = (d-pair, j-slice g) ------------
  const int dpair = tid & 63;
  const int g     = tid >> 6;                // 32 jp each
  const unsigned int* hTb =
      hT16 + ((size_t)b * 512 + js * 128 + g * 32) * 128 + dpair * 2;
  float cx[8][2];
#pragma unroll
  for (int r = 0; r < 8; ++r) { cx[r][0] = 0.f; cx[r][1] = 0.f; }

#define LDPV(Pa, Pb, V, jj) {                        \
    Pa = *(const uint4*)&Pt[g * 32 + (jj)][0];       \
    Pb = *(const uint4*)&Pt[g * 32 + (jj)][4];       \
    V  = *(const uint2*)&hTb[(size_t)(jj) * 128]; }

#define PVC(Pa, Pb, V) {                                      \
    cx[0][0] = dot2f(Pa.x, V.x, cx[0][0]);                    \
    cx[0][1] = dot2f(Pa.x, V.y, cx[0][1]);                    \
    cx[1][0] = dot2f(Pa.y, V.x, cx[1][0]);                    \
    cx[1][1] = dot2f(Pa.y, V.y, cx[1][1]);                    \
    cx[2][0] = dot2f(Pa.z, V.x, cx[2][0]);                    \
    cx[2][1] = dot2f(Pa.z, V.y, cx[2][1]);                    \
    cx[3][0] = dot2f(Pa.w, V.x, cx[3][0]);                    \
    cx[3][1] = dot2f(Pa.w, V.y, cx[3][1]);                    \
    cx[4][0] = dot2f(Pb.x, V.x, cx[4][0]);                    \
    cx[4][1] = dot2f(Pb.x, V.y, cx[4][1]);                    \
    cx[5][0] = dot2f(Pb.y, V.x, cx[5][0]);                    \
    cx[5][1] = dot2f(Pb.y, V.y, cx[5][1]);                    \
    cx[6][0] = dot2f(Pb.z, V.x, cx[6][0]);                    \
    cx[6][1] = dot2f(Pb.z, V.y, cx[6][1]);                    \
    cx[7][0] = dot2f(Pb.w, V.x, cx[7][0]);                    \
    cx[7][1] = dot2f(Pb.w, V.y, cx[7][1]); }

  {
    uint4 Pa0, Pb0, Pa1, Pb1; uint2 V0, V1;
    LDPV(Pa0, Pb0, V0, 0);
#pragma unroll 1
    for (int it = 0; it < 16; ++it) {
      LDPV(Pa1, Pb1, V1, 2 * it + 1);      // unconditional: <= 31
      PVC(Pa0, Pb0, V0);
      if (it < 15) LDPV(Pa0, Pb0, V0, 2 * it + 2);
      PVC(Pa1, Pb1, V1);
    }
  }

#pragma unroll
  for (int r = 0; r < 8; ++r) {
    float2 cv = {cx[r][0], cx[r][1]};
    *(float2*)&ctxp[g][r][dpair * 2] = cv;
  }
  __syncthreads();

  // final: reduce 4 g-slices, write ctx partial
#pragma unroll
  for (int k = 0; k < 4; ++k) {
    const int idx = tid + k * 256;           // 0..1023
    const int r = idx >> 7, d = idx & 127;
    ctxpart[((size_t)slot * 8 + r) * DD + d] =
        ctxp[0][r][d] + ctxp[1][r][d] + ctxp[2][r][d] + ctxp[3][r][d];
  }
}

// ---- K2: merge 4 j-split partials, normalize, write concat(h, ctx) ----
__global__ __launch_bounds__(256) void k_merge(const float* __restrict__ h,
                                               const float* __restrict__ ctxpart,
                                               const float* __restrict__ mlpart,
                                               float* __restrict__ out) {
  const int row = blockIdx.x * 2 + (threadIdx.x >> 7);   // 0..2047
  const int d   = threadIdx.x & 127;
  const int rg  = row >> 3;
  const int r   = row & 7;

  float mg[4], lg[4];
#pragma unroll
  for (int g = 0; g < 4; ++g) {
    const int sid = g * 256 + rg;
    mg[g] = mlpart[sid * 16 + r];
    lg[g] = mlpart[sid * 16 + 8 + r];
  }
  const float M = fmaxf(fmaxf(mg[0], mg[1]), fmaxf(mg[2], mg[3]));
  float L = 0.f, c = 0.f;
#pragma unroll
  for (int g = 0; g < 4; ++g) {
    const int sid = g * 256 + rg;
    const float wg = __expf(mg[g] - M);
    L = fmaf(lg[g], wg, L);
    c = fmaf(ctxpart[((size_t)sid * 8 + r) * DD + d], wg, c);
  }
  out[(size_t)row * 256 + d]       = h[(size_t)row * DD + d];
  out[(size_t)row * 256 + 128 + d] = c / L;
}

extern "C" void kernel_launch(void* const* d_in, const int* in_sizes, int n_in,
                              void* d_out, int out_size, void* d_ws, size_t ws_size,
                              hipStream_t stream) {
  const float* h  = (const float*)d_in[0];
  const int*   mk = (const int*)d_in[1];
  const float* w  = (const float*)d_in[2];
  float* out = (float*)d_out;

  char* ws = (char*)d_ws;
  float*        swj  = (float*)ws;                         // 8 KB
  float*        bias = (float*)(ws + 8192);                // 8 KB
  float4*       hT4  = (float4*)(ws + 16384);              // 1 MB
  unsigned int* hT16 = (unsigned int*)(ws + 16384 + 1048576);          // 512 KB
  float* ctxpart = (float*)(ws + 16384 + 1048576 + 524288);            // 4 MB
  float* mlpart  = (float*)(ws + 16384 + 1048576 + 524288 + 4194304);  // 64 KB

  hipLaunchKernelGGL(k_prep,  dim3(64),   dim3(256), 0, stream,
                     h, w, mk, hT4, hT16, swj, bias);
  hipLaunchKernelGGL(k_fused, dim3(1024), dim3(256), 0, stream,
                     h, hT4, hT16, swj, bias, ctxpart, mlpart);
  hipLaunchKernelGGL(k_merge, dim3(1024), dim3(256), 0, stream,
                     h, ctxpart, mlpart, out);
}